// Round 1
// baseline (342.515 us; speedup 1.0000x reference)
//
#include <hip/hip_runtime.h>

#define BLOCK 256
#define NPIX  (16 * 512 * 512)   // 4,194,304
#define IMG   (512 * 512)        // 262,144

// Workspace layout
struct WS {
    double acc[4];            // 0: sum w*(x-t)^2, 1: sum p*t, 2: sum p, 3: sum t
    unsigned int vmax[16];    // per-batch max distance (float bits; all values >= 0)
    float rows[16 * 512];     // w_edt[b, h=b, y]
};

// Kernel 1: exact EDT via expanding Chebyshev-ring search (cutoff r^2 >= best is
// exact since every ring-r pixel has dist^2 >= r^2). Produces only per-image max
// and the h==b row — the full field is never materialized.
__global__ __launch_bounds__(BLOCK) void edt_kernel(const float* __restrict__ tgt, WS* ws) {
    int idx = blockIdx.x * BLOCK + threadIdx.x;
    int b   = idx >> 18;
    int rem = idx & (IMG - 1);
    int h   = rem >> 9;
    int y   = rem & 511;
    const float* img = tgt + ((size_t)b << 18);
    float t = img[rem];

    float best = 0.0f;
    if (t != 0.0f) {
        best = 1e8f;
        for (int r = 1; r < 512; ++r) {
            float rr = (float)(r * r);
            if (rr >= best) break;
            int y0 = max(y - r, 0), y1 = min(y + r, 511);
            int hm = h - r, hp = h + r;
            if (hm >= 0) {
                const float* rp = img + (hm << 9);
                for (int yy = y0; yy <= y1; ++yy)
                    if (rp[yy] == 0.0f) {
                        int dx = yy - y;
                        best = fminf(best, (float)(r * r + dx * dx));
                    }
            }
            if (hp <= 511) {
                const float* rp = img + (hp << 9);
                for (int yy = y0; yy <= y1; ++yy)
                    if (rp[yy] == 0.0f) {
                        int dx = yy - y;
                        best = fminf(best, (float)(r * r + dx * dx));
                    }
            }
            int h0 = max(hm + 1, 0), h1 = min(hp - 1, 511);
            if (y - r >= 0) {
                for (int hh = h0; hh <= h1; ++hh)
                    if (img[(hh << 9) + (y - r)] == 0.0f) {
                        int dy = hh - h;
                        best = fminf(best, (float)(dy * dy + r * r));
                    }
            }
            if (y + r <= 511) {
                for (int hh = h0; hh <= h1; ++hh)
                    if (img[(hh << 9) + (y + r)] == 0.0f) {
                        int dy = hh - h;
                        best = fminf(best, (float)(dy * dy + r * r));
                    }
            }
        }
    }
    float dist = (t != 0.0f) ? sqrtf(best) : 0.0f;

    if (h == b) ws->rows[(b << 9) + y] = dist;

    // block max reduce -> atomicMax (float bits monotone for non-negative)
    float m = dist;
    #pragma unroll
    for (int o = 32; o > 0; o >>= 1) m = fmaxf(m, __shfl_down(m, o));
    __shared__ float smax[BLOCK / 64];
    int lane = threadIdx.x & 63, wid = threadIdx.x >> 6;
    if (lane == 0) smax[wid] = m;
    __syncthreads();
    if (threadIdx.x == 0) {
        float bm = smax[0];
        #pragma unroll
        for (int i = 1; i < BLOCK / 64; ++i) bm = fmaxf(bm, smax[i]);
        atomicMax(&ws->vmax[b], __float_as_uint(bm));
    }
}

// Kernel 2: streaming reduction of the 4 scalar sums over all pixels (float4).
__global__ __launch_bounds__(BLOCK) void loss_kernel(const float4* __restrict__ x4,
                                                     const float4* __restrict__ t4,
                                                     WS* ws) {
    const float4* rows4 = (const float4*)ws->rows;
    float s0 = 0.f, s1 = 0.f, s2 = 0.f, s3 = 0.f;
    const int total4 = NPIX / 4;  // 1,048,576
    for (int i = blockIdx.x * BLOCK + threadIdx.x; i < total4; i += gridDim.x * BLOCK) {
        int b  = i >> 16;          // 65536 float4 per image
        int y4 = i & 127;          // 128 float4 per row
        float v = __uint_as_float(ws->vmax[b]);
        float4 xv = x4[i];
        float4 tv = t4[i];
        float4 rv = rows4[(b << 7) + y4];
        {
            float w = tv.x * (v - rv.x) + 0.001f; float d = xv.x - tv.x;
            s0 += w * d * d; float p = 1.0f / (1.0f + expf(-xv.x));
            s1 += p * tv.x; s2 += p; s3 += tv.x;
        }
        {
            float w = tv.y * (v - rv.y) + 0.001f; float d = xv.y - tv.y;
            s0 += w * d * d; float p = 1.0f / (1.0f + expf(-xv.y));
            s1 += p * tv.y; s2 += p; s3 += tv.y;
        }
        {
            float w = tv.z * (v - rv.z) + 0.001f; float d = xv.z - tv.z;
            s0 += w * d * d; float p = 1.0f / (1.0f + expf(-xv.z));
            s1 += p * tv.z; s2 += p; s3 += tv.z;
        }
        {
            float w = tv.w * (v - rv.w) + 0.001f; float d = xv.w - tv.w;
            s0 += w * d * d; float p = 1.0f / (1.0f + expf(-xv.w));
            s1 += p * tv.w; s2 += p; s3 += tv.w;
        }
    }
    // block reduce 4 floats
    #pragma unroll
    for (int o = 32; o > 0; o >>= 1) {
        s0 += __shfl_down(s0, o);
        s1 += __shfl_down(s1, o);
        s2 += __shfl_down(s2, o);
        s3 += __shfl_down(s3, o);
    }
    __shared__ float4 ssum[BLOCK / 64];
    int lane = threadIdx.x & 63, wid = threadIdx.x >> 6;
    if (lane == 0) ssum[wid] = make_float4(s0, s1, s2, s3);
    __syncthreads();
    if (threadIdx.x == 0) {
        float4 a = ssum[0];
        #pragma unroll
        for (int i = 1; i < BLOCK / 64; ++i) {
            a.x += ssum[i].x; a.y += ssum[i].y; a.z += ssum[i].z; a.w += ssum[i].w;
        }
        atomicAdd(&ws->acc[0], (double)a.x);
        atomicAdd(&ws->acc[1], (double)a.y);
        atomicAdd(&ws->acc[2], (double)a.z);
        atomicAdd(&ws->acc[3], (double)a.w);
    }
}

// Kernel 3: finalize the two scalars in double precision.
__global__ void finalize_kernel(const WS* __restrict__ ws, float* __restrict__ out) {
    double wsum = ws->acc[0];
    double inter = ws->acc[1];
    double sp = ws->acc[2];
    double st = ws->acc[3];
    double wmse = wsum / (double)NPIX;
    out[0] = (float)(0.6 * wmse);
    double dice = 1.0 - (2.0 * inter + 1e-6) / (sp + st + 1e-6);
    out[1] = (float)(1.0 * dice);
}

extern "C" void kernel_launch(void* const* d_in, const int* in_sizes, int n_in,
                              void* d_out, int out_size, void* d_ws, size_t ws_size,
                              hipStream_t stream) {
    const float* inp = (const float*)d_in[0];
    const float* tgt = (const float*)d_in[1];
    float* out = (float*)d_out;
    WS* ws = (WS*)d_ws;

    hipMemsetAsync(d_ws, 0, sizeof(WS), stream);
    edt_kernel<<<NPIX / BLOCK, BLOCK, 0, stream>>>(tgt, ws);
    loss_kernel<<<1024, BLOCK, 0, stream>>>((const float4*)inp, (const float4*)tgt, ws);
    finalize_kernel<<<1, 1, 0, stream>>>(ws, out);
}

// Round 2
// 146.763 us; speedup vs baseline: 2.3338x; 2.3338x over previous
//
#include <hip/hip_runtime.h>

#define W     512
#define IMG   (512 * 512)
#define NB    16
#define NPIX  (NB * IMG)
#define TILE_H 16
#define APRON  16
#define LROWS  (TILE_H + 2 * APRON)   // 48
#define BLOCK  256

struct WS {
    unsigned int vmax[16];     // must be zeroed each launch (atomicMax target)
    float rows[16 * 512];      // w_edt[b, h=b, y] — fully written by edt tile-0 blocks
    float4 partial[512];       // per-block loss partial sums — fully written
};

// Nearest zero-pixel horizontal offset |dx| to column y in a 512-bit zeros-mask
// (bit set = pixel==0). Returns up to 1024 if row has no zeros.
__device__ __forceinline__ int nearest_dx(const unsigned long long* __restrict__ RW, int y) {
    int w = y >> 6, off = y & 63;
    int dr = 1024;
    unsigned long long m = RW[w] >> off;          // bit0 == column y
    if (m) dr = __builtin_ctzll(m);
    else {
        for (int ww = w + 1; ww < 8; ++ww)
            if (RW[ww]) { dr = (ww << 6) + __builtin_ctzll(RW[ww]) - y; break; }
    }
    int dl = 1024;
    unsigned long long ml = RW[w] << (63 - off);  // bit63 == column y
    if (ml) dl = __builtin_clzll(ml);
    else {
        for (int ww = w - 1; ww >= 0; --ww)
            if (RW[ww]) { dl = y - ((ww << 6) + 63 - __builtin_clzll(RW[ww])); break; }
    }
    int d = min(dr, dl);
    return min(d, 1024);
}

// Exact EDT via bit-packed LDS row scans. Each block: one 16-row x 512-col tile
// plus 16-row apron above/below, packed 1 bit/pixel via wave ballot.
__global__ __launch_bounds__(BLOCK) void edt_kernel(const float* __restrict__ tgt,
                                                    WS* __restrict__ ws) {
    __shared__ unsigned long long zm[LROWS][8];   // 3 KB zeros-mask
    int blk  = blockIdx.x;
    int b    = blk >> 5;          // 32 tiles per image
    int tile = blk & 31;
    int h0   = tile * TILE_H;
    const float* img = tgt + (size_t)b * IMG;

    int wave = threadIdx.x >> 6, lane = threadIdx.x & 63;
    // Pack LROWS*8 = 384 u64 words; wave-uniform word index, coalesced 256B loads.
    for (int wi = wave; wi < LROWS * 8; wi += 4) {
        int lr = wi >> 3, wc = wi & 7;
        int gh = h0 - APRON + lr;
        unsigned long long m = 0ULL;
        if (gh >= 0 && gh < W) {
            float v = img[(gh << 9) + (wc << 6) + lane];
            m = __ballot(v == 0.0f);
        }
        if (lane == 0) zm[lr][wc] = m;
    }
    __syncthreads();

    float maxd = 0.0f;
    for (int k = 0; k < TILE_H * W / BLOCK; ++k) {   // 32 pixels per thread
        int p  = threadIdx.x + (k << 8);
        int y  = p & (W - 1);
        int hl = p >> 9;
        int h  = h0 + hl;
        int lr = hl + APRON;
        bool nz = ((zm[lr][y >> 6] >> (y & 63)) & 1ULL) == 0ULL;
        float dist = 0.0f;
        if (nz) {
            int best = 1 << 30;
            for (int dh = 0; dh <= APRON; ++dh) {
                if (dh * dh >= best) break;
                int dx1 = nearest_dx(zm[lr + dh], y);
                best = min(best, dh * dh + dx1 * dx1);
                if (dh) {
                    int dx2 = nearest_dx(zm[lr - dh], y);
                    best = min(best, dh * dh + dx2 * dx2);
                }
            }
            // Exactness guard: unsearched pixels have d^2 >= (APRON+1)^2.
            if (best > (APRON + 1) * (APRON + 1)) {
                for (int dh = APRON + 1; dh < W; ++dh) {
                    if (dh * dh >= best) break;
                    for (int s = 0; s < 2; ++s) {
                        int gh = s ? h - dh : h + dh;
                        if (gh < 0 || gh >= W) continue;
                        const float* rp = img + (gh << 9);
                        for (int yy = 0; yy < W; ++yy)
                            if (rp[yy] == 0.0f) {
                                int dx = yy - y;
                                best = min(best, dh * dh + dx * dx);
                            }
                    }
                }
            }
            dist = sqrtf((float)best);
        }
        if (h == b) ws->rows[(b << 9) + y] = dist;
        maxd = fmaxf(maxd, dist);
    }

    // block max reduce -> atomicMax (float bits monotone for non-negative)
    #pragma unroll
    for (int o = 32; o > 0; o >>= 1) maxd = fmaxf(maxd, __shfl_down(maxd, o));
    __shared__ float smax[BLOCK / 64];
    if (lane == 0) smax[wave] = maxd;
    __syncthreads();
    if (threadIdx.x == 0) {
        float bm = smax[0];
        #pragma unroll
        for (int i = 1; i < BLOCK / 64; ++i) bm = fmaxf(bm, smax[i]);
        atomicMax(&ws->vmax[b], __float_as_uint(bm));
    }
}

// Streaming reduction of the 4 scalar sums (float4 loads, per-block partials).
__global__ __launch_bounds__(BLOCK) void loss_kernel(const float4* __restrict__ x4,
                                                     const float4* __restrict__ t4,
                                                     WS* __restrict__ ws) {
    const float4* rows4 = (const float4*)ws->rows;
    float s0 = 0.f, s1 = 0.f, s2 = 0.f, s3 = 0.f;
    const int total4 = NPIX / 4;  // 1,048,576 = 512 blocks * 256 threads * 8
    for (int i = blockIdx.x * BLOCK + threadIdx.x; i < total4; i += 512 * BLOCK) {
        int b  = i >> 16;          // 65536 float4 per image
        int y4 = i & 127;          // 128 float4 per row
        float v = __uint_as_float(ws->vmax[b]);
        float4 xv = x4[i];
        float4 tv = t4[i];
        float4 rv = rows4[(b << 7) + y4];
        {
            float w = tv.x * (v - rv.x) + 0.001f; float d = xv.x - tv.x;
            s0 += w * d * d; float p = 1.0f / (1.0f + __expf(-xv.x));
            s1 += p * tv.x; s2 += p; s3 += tv.x;
        }
        {
            float w = tv.y * (v - rv.y) + 0.001f; float d = xv.y - tv.y;
            s0 += w * d * d; float p = 1.0f / (1.0f + __expf(-xv.y));
            s1 += p * tv.y; s2 += p; s3 += tv.y;
        }
        {
            float w = tv.z * (v - rv.z) + 0.001f; float d = xv.z - tv.z;
            s0 += w * d * d; float p = 1.0f / (1.0f + __expf(-xv.z));
            s1 += p * tv.z; s2 += p; s3 += tv.z;
        }
        {
            float w = tv.w * (v - rv.w) + 0.001f; float d = xv.w - tv.w;
            s0 += w * d * d; float p = 1.0f / (1.0f + __expf(-xv.w));
            s1 += p * tv.w; s2 += p; s3 += tv.w;
        }
    }
    #pragma unroll
    for (int o = 32; o > 0; o >>= 1) {
        s0 += __shfl_down(s0, o);
        s1 += __shfl_down(s1, o);
        s2 += __shfl_down(s2, o);
        s3 += __shfl_down(s3, o);
    }
    __shared__ float4 ssum[BLOCK / 64];
    int lane = threadIdx.x & 63, wid = threadIdx.x >> 6;
    if (lane == 0) ssum[wid] = make_float4(s0, s1, s2, s3);
    __syncthreads();
    if (threadIdx.x == 0) {
        float4 a = ssum[0];
        #pragma unroll
        for (int i = 1; i < BLOCK / 64; ++i) {
            a.x += ssum[i].x; a.y += ssum[i].y; a.z += ssum[i].z; a.w += ssum[i].w;
        }
        ws->partial[blockIdx.x] = a;
    }
}

// Finalize: reduce 512 partials in double, emit the two scalars.
__global__ __launch_bounds__(BLOCK) void finalize_kernel(const WS* __restrict__ ws,
                                                         float* __restrict__ out) {
    int tid = threadIdx.x;
    float4 p0 = ws->partial[tid];
    float4 p1 = ws->partial[tid + 256];
    double s0 = (double)p0.x + p1.x;
    double s1 = (double)p0.y + p1.y;
    double s2 = (double)p0.z + p1.z;
    double s3 = (double)p0.w + p1.w;
    #pragma unroll
    for (int o = 32; o > 0; o >>= 1) {
        s0 += __shfl_down(s0, o);
        s1 += __shfl_down(s1, o);
        s2 += __shfl_down(s2, o);
        s3 += __shfl_down(s3, o);
    }
    __shared__ double sh[4][4];
    int lane = tid & 63, wid = tid >> 6;
    if (lane == 0) { sh[wid][0] = s0; sh[wid][1] = s1; sh[wid][2] = s2; sh[wid][3] = s3; }
    __syncthreads();
    if (tid == 0) {
        double a0 = 0, a1 = 0, a2 = 0, a3 = 0;
        #pragma unroll
        for (int i = 0; i < 4; ++i) { a0 += sh[i][0]; a1 += sh[i][1]; a2 += sh[i][2]; a3 += sh[i][3]; }
        out[0] = (float)(0.6 * (a0 / (double)NPIX));
        out[1] = (float)(1.0 - (2.0 * a1 + 1e-6) / (a2 + a3 + 1e-6));
    }
}

extern "C" void kernel_launch(void* const* d_in, const int* in_sizes, int n_in,
                              void* d_out, int out_size, void* d_ws, size_t ws_size,
                              hipStream_t stream) {
    const float* inp = (const float*)d_in[0];
    const float* tgt = (const float*)d_in[1];
    float* out = (float*)d_out;
    WS* ws = (WS*)d_ws;

    hipMemsetAsync(d_ws, 0, sizeof(unsigned int) * 16, stream);  // vmax only
    edt_kernel<<<NB * 32, BLOCK, 0, stream>>>(tgt, ws);
    loss_kernel<<<512, BLOCK, 0, stream>>>((const float4*)inp, (const float4*)tgt, ws);
    finalize_kernel<<<1, BLOCK, 0, stream>>>(ws, out);
}

// Round 3
// 120.195 us; speedup vs baseline: 2.8497x; 1.2210x over previous
//
#include <hip/hip_runtime.h>

#define W      512
#define IMG    (512 * 512)
#define NB     16
#define NPIX   (NB * IMG)
#define TILE_H 16
#define APRON  8
#define LROWS  (TILE_H + 2 * APRON)   // 32
#define BLOCK  256
#define LOSS_BLOCKS 1024

struct WS {
    unsigned int vmax[16];     // per-batch max of best (int d^2); zeroed each launch
    float rows[16 * 512];      // w_edt[b, h=b, y] — fully written by tile-0 blocks
    float4 partial[LOSS_BLOCKS];
};

// Exact EDT via separable bit-trick:
//   D[r][y]   = nearest-zero distance within row r (1-D, bit-window, branch-free)
//   best(h,y) = min_{|dh|<=8} dh^2 + D[h+dh][y]^2
// Guard: searched set is {|dh|<=8, |dx|<=63}; complement d^2 >= 81, so best<=81 is exact.
__global__ __launch_bounds__(BLOCK) void edt_kernel(const float* __restrict__ tgt,
                                                    WS* __restrict__ ws) {
    __shared__ unsigned long long zm[LROWS][10];   // zeros-mask, cols 1..8 data, 0/9 sentinel
    __shared__ unsigned short Dd[LROWS][W];        // 32 KB row-profile distances

    int blk  = blockIdx.x;
    int b    = blk >> 5;          // 32 tiles per image
    int tile = blk & 31;
    int h0   = tile * TILE_H;
    const float* img = tgt + (size_t)b * IMG;

    int tid  = threadIdx.x;
    int wave = tid >> 6, lane = tid & 63;

    // ---- Phase 1: pack zeros-mask (1 bit/pixel) via ballot, coalesced 256B loads ----
    for (int wi = wave; wi < LROWS * 8; wi += 4) {
        int lr = wi >> 3, wc = wi & 7;
        int gh = h0 - APRON + lr;
        unsigned long long m = 0ULL;
        if (gh >= 0 && gh < W) {
            float v = img[(gh << 9) + (wc << 6) + lane];
            m = __ballot(v == 0.0f);
        }
        if (lane == 0) zm[lr][wc + 1] = m;
    }
    for (int i = tid; i < LROWS; i += BLOCK) { zm[i][0] = 0ULL; zm[i][9] = 0ULL; }
    __syncthreads();

    // ---- Phase 2: 1-D row profiles. Per unit: 3 wave-uniform broadcast words,
    //      per-lane 128-bit window, ctz/clz. Branch-free. ----
    for (int u = wave; u < LROWS * 8; u += 4) {
        int lr = u >> 3, wc = u & 7;
        unsigned long long Wm = zm[lr][wc];
        unsigned long long Wc = zm[lr][wc + 1];
        unsigned long long Wp = zm[lr][wc + 2];
        int off = lane;
        // right window: bits y..y+63
        unsigned long long wr = (Wc >> off) | (off ? (Wp << (64 - off)) : 0ULL);
        int dr = wr ? __builtin_ctzll(wr) : 1000;
        // left window: msb = bit y-1 ... lsb = bit y-64
        unsigned long long vl = off ? ((Wc << (64 - off)) | (Wm >> off)) : Wm;
        int dl = vl ? (1 + __builtin_clzll(vl)) : 1000;
        int d = min(min(dr, dl), 1000);
        Dd[lr][(wc << 6) + lane] = (unsigned short)d;
    }
    __syncthreads();

    // ---- Phase 3: combine, 17 independent LDS u16 reads/pixel, no divergence ----
    unsigned int bmax = 0;
    for (int k = 0; k < TILE_H * W / BLOCK; ++k) {   // 32 pixels/thread
        int p  = tid + (k << 8);
        int y  = p & (W - 1);
        int hl = p >> 9;
        int lr = hl + APRON;
        int best = 1 << 30;
        #pragma unroll
        for (int dh = -APRON; dh <= APRON; ++dh) {
            int d = Dd[lr + dh][y];
            best = min(best, dh * dh + d * d);
        }
        if (best > 81) {   // exactness fallback — statistically never taken
            int h = h0 + hl;
            best = 100000000;   // matches reference BIG when no zeros exist
            for (int gh = 0; gh < W; ++gh) {
                int dhh = gh - h;
                if (dhh * dhh >= best) continue;
                const float* rp = img + (gh << 9);
                for (int yy = 0; yy < W; ++yy)
                    if (rp[yy] == 0.0f) {
                        int dx = yy - y;
                        best = min(best, dhh * dhh + dx * dx);
                    }
            }
        }
        if (h0 + hl == b) ws->rows[(b << 9) + y] = sqrtf((float)best);
        bmax = max(bmax, (unsigned int)best);
    }

    // block max (int d^2; sqrt is monotone) -> atomicMax
    #pragma unroll
    for (int o = 32; o > 0; o >>= 1) bmax = max(bmax, (unsigned int)__shfl_down(bmax, o));
    __shared__ unsigned int smax[BLOCK / 64];
    if (lane == 0) smax[wave] = bmax;
    __syncthreads();
    if (tid == 0) {
        unsigned int bm = smax[0];
        #pragma unroll
        for (int i = 1; i < BLOCK / 64; ++i) bm = max(bm, smax[i]);
        atomicMax(&ws->vmax[b], bm);
    }
}

// Streaming reduction of the 4 scalar sums (float4 loads, per-block partials).
__global__ __launch_bounds__(BLOCK) void loss_kernel(const float4* __restrict__ x4,
                                                     const float4* __restrict__ t4,
                                                     WS* __restrict__ ws) {
    const float4* rows4 = (const float4*)ws->rows;
    float s0 = 0.f, s1 = 0.f, s2 = 0.f, s3 = 0.f;
    const int total4 = NPIX / 4;  // 1,048,576
    for (int i = blockIdx.x * BLOCK + threadIdx.x; i < total4; i += LOSS_BLOCKS * BLOCK) {
        int b  = i >> 16;          // 65536 float4 per image
        int y4 = i & 127;          // 128 float4 per row
        float v = sqrtf((float)ws->vmax[b]);
        float4 xv = x4[i];
        float4 tv = t4[i];
        float4 rv = rows4[(b << 7) + y4];
        {
            float w = tv.x * (v - rv.x) + 0.001f; float d = xv.x - tv.x;
            s0 += w * d * d; float p = 1.0f / (1.0f + __expf(-xv.x));
            s1 += p * tv.x; s2 += p; s3 += tv.x;
        }
        {
            float w = tv.y * (v - rv.y) + 0.001f; float d = xv.y - tv.y;
            s0 += w * d * d; float p = 1.0f / (1.0f + __expf(-xv.y));
            s1 += p * tv.y; s2 += p; s3 += tv.y;
        }
        {
            float w = tv.z * (v - rv.z) + 0.001f; float d = xv.z - tv.z;
            s0 += w * d * d; float p = 1.0f / (1.0f + __expf(-xv.z));
            s1 += p * tv.z; s2 += p; s3 += tv.z;
        }
        {
            float w = tv.w * (v - rv.w) + 0.001f; float d = xv.w - tv.w;
            s0 += w * d * d; float p = 1.0f / (1.0f + __expf(-xv.w));
            s1 += p * tv.w; s2 += p; s3 += tv.w;
        }
    }
    #pragma unroll
    for (int o = 32; o > 0; o >>= 1) {
        s0 += __shfl_down(s0, o);
        s1 += __shfl_down(s1, o);
        s2 += __shfl_down(s2, o);
        s3 += __shfl_down(s3, o);
    }
    __shared__ float4 ssum[BLOCK / 64];
    int lane = threadIdx.x & 63, wid = threadIdx.x >> 6;
    if (lane == 0) ssum[wid] = make_float4(s0, s1, s2, s3);
    __syncthreads();
    if (threadIdx.x == 0) {
        float4 a = ssum[0];
        #pragma unroll
        for (int i = 1; i < BLOCK / 64; ++i) {
            a.x += ssum[i].x; a.y += ssum[i].y; a.z += ssum[i].z; a.w += ssum[i].w;
        }
        ws->partial[blockIdx.x] = a;
    }
}

// Finalize: reduce LOSS_BLOCKS partials in double, emit the two scalars.
__global__ __launch_bounds__(BLOCK) void finalize_kernel(const WS* __restrict__ ws,
                                                         float* __restrict__ out) {
    int tid = threadIdx.x;
    double s0 = 0, s1 = 0, s2 = 0, s3 = 0;
    #pragma unroll
    for (int j = 0; j < LOSS_BLOCKS / BLOCK; ++j) {
        float4 p = ws->partial[tid + j * BLOCK];
        s0 += p.x; s1 += p.y; s2 += p.z; s3 += p.w;
    }
    #pragma unroll
    for (int o = 32; o > 0; o >>= 1) {
        s0 += __shfl_down(s0, o);
        s1 += __shfl_down(s1, o);
        s2 += __shfl_down(s2, o);
        s3 += __shfl_down(s3, o);
    }
    __shared__ double sh[4][4];
    int lane = tid & 63, wid = tid >> 6;
    if (lane == 0) { sh[wid][0] = s0; sh[wid][1] = s1; sh[wid][2] = s2; sh[wid][3] = s3; }
    __syncthreads();
    if (tid == 0) {
        double a0 = 0, a1 = 0, a2 = 0, a3 = 0;
        #pragma unroll
        for (int i = 0; i < 4; ++i) { a0 += sh[i][0]; a1 += sh[i][1]; a2 += sh[i][2]; a3 += sh[i][3]; }
        out[0] = (float)(0.6 * (a0 / (double)NPIX));
        out[1] = (float)(1.0 - (2.0 * a1 + 1e-6) / (a2 + a3 + 1e-6));
    }
}

extern "C" void kernel_launch(void* const* d_in, const int* in_sizes, int n_in,
                              void* d_out, int out_size, void* d_ws, size_t ws_size,
                              hipStream_t stream) {
    const float* inp = (const float*)d_in[0];
    const float* tgt = (const float*)d_in[1];
    float* out = (float*)d_out;
    WS* ws = (WS*)d_ws;

    hipMemsetAsync(d_ws, 0, sizeof(unsigned int) * 16, stream);  // vmax only
    edt_kernel<<<NB * 32, BLOCK, 0, stream>>>(tgt, ws);
    loss_kernel<<<LOSS_BLOCKS, BLOCK, 0, stream>>>((const float4*)inp, (const float4*)tgt, ws);
    finalize_kernel<<<1, BLOCK, 0, stream>>>(ws, out);
}